// Round 6
// baseline (185.348 us; speedup 1.0000x reference)
//
#include <hip/hip_runtime.h>
#include <hip/hip_cooperative_groups.h>
#include <math.h>

#define K_DIM 4096
#define N_DIM 4096

typedef float f32x4 __attribute__((ext_vector_type(4)));

namespace cg = cooperative_groups;

// PROCESS one row held in XV: dot vs c (L3/L2-hot), wave reduce, gelu, add+NT-store.
#define PROCESS(XV, ROFF)                                                        \
    do {                                                                         \
        float a0 = 0.f, a1 = 0.f, a2 = 0.f, a3 = 0.f;                            \
        _Pragma("unroll")                                                        \
        for (int i = 0; i < 16; ++i) {                                           \
            f32x4 cvv = c4[lane + i * 64];                                       \
            a0 += XV[i].x * cvv.x;                                               \
            a1 += XV[i].y * cvv.y;                                               \
            a2 += XV[i].z * cvv.z;                                               \
            a3 += XV[i].w * cvv.w;                                               \
        }                                                                        \
        float acc = (a0 + a1) + (a2 + a3);                                       \
        _Pragma("unroll")                                                        \
        for (int off = 32; off > 0; off >>= 1) acc += __shfl_xor(acc, off, 64);  \
        float d = acc * (1.0f / (float)N_DIM) + bt;                              \
        float inner = 0.7978845608028654f * (d + 0.044715f * d * d * d);         \
        float e  = __expf(2.0f * inner);                                         \
        float g  = 0.5f * d * (1.0f + (1.0f - 2.0f / (e + 1.0f)));               \
        _Pragma("unroll")                                                        \
        for (int i = 0; i < 16; ++i) {                                           \
            f32x4 o = XV[i] + g;                                                 \
            __builtin_nontemporal_store(o, &o4[(size_t)(ROFF) * 1024 + lane + i * 64]); \
        }                                                                        \
    } while (0)

#define LOADB(BUF, R)                                                            \
    do {                                                                         \
        _Pragma("unroll")                                                        \
        for (int i = 0; i < 16; ++i)                                             \
            BUF[i] = __builtin_nontemporal_load(&x4[(size_t)(R) * 1024 + lane + i * 64]); \
    } while (0)

// One cooperative kernel. 256 blocks x 512 threads (8 waves). 1 block/CU.
// Wave wid owns x rows [wid*8, wid*8+8) and W rows {wid*2, wid*2+1}.
__global__ void __launch_bounds__(512, 2) fused_kernel(const float* __restrict__ x,
                                                       const float* __restrict__ W,
                                                       const float* __restrict__ bias,
                                                       const float* __restrict__ subtract,
                                                       float* __restrict__ c,
                                                       float* __restrict__ out) {
    const int t = threadIdx.x;
    const int wave = t >> 6, lane = t & 63;
    const int wid = blockIdx.x * 8 + wave;        // 0..2047
    __shared__ float sbt;

    const f32x4* x4 = reinterpret_cast<const f32x4*>(x) + (size_t)wid * 8 * (K_DIM / 4);
    f32x4*       o4 = reinterpret_cast<f32x4*>(out)     + (size_t)wid * 8 * (K_DIM / 4);
    const f32x4* c4 = reinterpret_cast<const f32x4*>(c);

    f32x4 xa[16], xb[16];

    // ---- Phase A0: issue row-0 x prefetch; stays in flight under colsum ----
    LOADB(xa, 0);

    // ---- Phase A1: colsum — 2 W rows per wave ----
#pragma unroll 2
    for (int rr = 0; rr < 2; ++rr) {
        const int k = wid * 2 + rr;
        const f32x4* wr = reinterpret_cast<const f32x4*>(W + (size_t)k * N_DIM);
        float a0 = 0.f, a1 = 0.f, a2 = 0.f, a3 = 0.f;
#pragma unroll
        for (int i = 0; i < 16; ++i) {
            f32x4 v = __builtin_nontemporal_load(&wr[lane + i * 64]);
            a0 += v.x; a1 += v.y; a2 += v.z; a3 += v.w;
        }
        float acc = (a0 + a1) + (a2 + a3);
#pragma unroll
        for (int off = 32; off > 0; off >>= 1) acc += __shfl_xor(acc, off, 64);
        if (lane == 0) c[k] = acc;
    }

    // ---- Phase A2: wave 0 computes bterm into LDS ----
    if (wave == 0) {
        const f32x4* b4 = reinterpret_cast<const f32x4*>(bias);
        const f32x4* s4 = reinterpret_cast<const f32x4*>(subtract);
        float acc = 0.f;
#pragma unroll
        for (int i = 0; i < 16; ++i) {
            f32x4 bv = b4[lane + i * 64];
            f32x4 sv = s4[lane + i * 64];
            acc += (bv.x - sv.x) + (bv.y - sv.y) + (bv.z - sv.z) + (bv.w - sv.w);
        }
#pragma unroll
        for (int off = 32; off > 0; off >>= 1) acc += __shfl_xor(acc, off, 64);
        if (lane == 0) sbt = acc * (1.0f / (float)N_DIM);
    }

    // ---- device-scope barrier: c + sbt visible to all ----
    cg::this_grid().sync();
    const float bt = sbt;

    // ---- Phase B: 8 rows, 2-deep pipeline (xa holds row 0 already) ----
    LOADB(xb, 1); PROCESS(xa, 0);
    LOADB(xa, 2); PROCESS(xb, 1);
    LOADB(xb, 3); PROCESS(xa, 2);
    LOADB(xa, 4); PROCESS(xb, 3);
    LOADB(xb, 5); PROCESS(xa, 4);
    LOADB(xa, 6); PROCESS(xb, 5);
    LOADB(xb, 7); PROCESS(xa, 6);
    PROCESS(xb, 7);
}

extern "C" void kernel_launch(void* const* d_in, const int* in_sizes, int n_in,
                              void* d_out, int out_size, void* d_ws, size_t ws_size,
                              hipStream_t stream) {
    const float* x        = (const float*)d_in[0];   // (M, K)
    const float* W        = (const float*)d_in[1];   // (K, N)
    const float* bias     = (const float*)d_in[2];   // (N,)
    const float* subtract = (const float*)d_in[3];   // (N,)
    float* out = (float*)d_out;
    float* c   = (float*)d_ws;                       // K_DIM floats

    const int M = in_sizes[0] / K_DIM;               // 16384
    const int blocks = M / 64;                       // 8 waves x 8 rows per block -> 256

    void* args[] = { (void*)&x, (void*)&W, (void*)&bias, (void*)&subtract,
                     (void*)&c, (void*)&out };
    hipLaunchCooperativeKernel((const void*)fused_kernel, dim3(blocks), dim3(512),
                               args, 0, stream);
}

// Round 7
// 100.566 us; speedup vs baseline: 1.8431x; 1.8431x over previous
//
#include <hip/hip_runtime.h>
#include <math.h>

#define K_DIM 4096
#define N_DIM 4096

typedef float f32x4 __attribute__((ext_vector_type(4)));

// ---------------- Kernel 1: c[k] = sum_n W[k][n]; extra block does bterm ----------------
// W is read once ever -> NT loads (keep L3 for x).
__global__ void __launch_bounds__(256) colsum_kernel(const float* __restrict__ W,
                                                     const float* __restrict__ bias,
                                                     const float* __restrict__ subtract,
                                                     float* __restrict__ c,
                                                     float* __restrict__ bterm) {
    const int t = threadIdx.x;
    __shared__ float s[4];
    const int wave = t >> 6, lane = t & 63;

    if (blockIdx.x < K_DIM) {
        const int k = blockIdx.x;
        const f32x4* row = reinterpret_cast<const f32x4*>(W + (size_t)k * N_DIM);
        float acc = 0.f;
#pragma unroll
        for (int i = 0; i < N_DIM / 4 / 256; ++i) {   // 4 iterations
            f32x4 v = __builtin_nontemporal_load(&row[t + i * 256]);
            acc += (v.x + v.y) + (v.z + v.w);
        }
#pragma unroll
        for (int off = 32; off > 0; off >>= 1) acc += __shfl_down(acc, off, 64);
        if (lane == 0) s[wave] = acc;
        __syncthreads();
        if (t == 0) c[k] = (s[0] + s[1]) + (s[2] + s[3]);
    } else {
        float acc = 0.f;
        for (int i = t; i < N_DIM; i += 256) acc += bias[i] - subtract[i];
#pragma unroll
        for (int off = 32; off > 0; off >>= 1) acc += __shfl_down(acc, off, 64);
        if (lane == 0) s[wave] = acc;
        __syncthreads();
        if (t == 0) bterm[0] = ((s[0] + s[1]) + (s[2] + s[3])) * (1.0f / (float)N_DIM);
    }
}

// ---------------- Kernel 2: persistent waves, 4 rows/wave, software-pipelined ----------------
// x loads: PLAIN CACHING (allocate in L3 -> cross-replay residency).
// out stores: NT (write-once, don't evict x from L3).
// c: plain (L2-hot).

#define PROCESS(XV, ROFF)                                                        \
    do {                                                                         \
        float a0 = 0.f, a1 = 0.f, a2 = 0.f, a3 = 0.f;                            \
        _Pragma("unroll")                                                        \
        for (int i = 0; i < 16; ++i) {                                           \
            f32x4 cvv = c4[lane + i * 64];                                       \
            a0 += XV[i].x * cvv.x;                                               \
            a1 += XV[i].y * cvv.y;                                               \
            a2 += XV[i].z * cvv.z;                                               \
            a3 += XV[i].w * cvv.w;                                               \
        }                                                                        \
        float acc = (a0 + a1) + (a2 + a3);                                       \
        _Pragma("unroll")                                                        \
        for (int off = 32; off > 0; off >>= 1) acc += __shfl_xor(acc, off, 64);  \
        float d = acc * (1.0f / (float)N_DIM) + bt;                              \
        float inner = 0.7978845608028654f * (d + 0.044715f * d * d * d);         \
        float e  = __expf(2.0f * inner);                                         \
        float g  = 0.5f * d * (1.0f + (1.0f - 2.0f / (e + 1.0f)));               \
        _Pragma("unroll")                                                        \
        for (int i = 0; i < 16; ++i) {                                           \
            f32x4 o = XV[i] + g;                                                 \
            __builtin_nontemporal_store(o, &orow[(size_t)(ROFF) * 1024 + lane + i * 64]); \
        }                                                                        \
    } while (0)

#define LOADB(BUF, R)                                                            \
    do {                                                                         \
        _Pragma("unroll")                                                        \
        for (int i = 0; i < 16; ++i)                                             \
            BUF[i] = x4[(size_t)(R) * 1024 + lane + i * 64];                     \
    } while (0)

__global__ void __launch_bounds__(256) rowfuse_kernel(const float* __restrict__ x,
                                                      const float* __restrict__ c,
                                                      const float* __restrict__ bterm,
                                                      float* __restrict__ out) {
    const int t = threadIdx.x;
    const int wave = t >> 6, lane = t & 63;
    const size_t w = (size_t)blockIdx.x * 4 + wave;   // 4096 waves, 4 rows each

    const f32x4* c4 = reinterpret_cast<const f32x4*>(c);
    const f32x4* x4 = reinterpret_cast<const f32x4*>(x) + w * 4 * (K_DIM / 4);
    f32x4* orow     = reinterpret_cast<f32x4*>(out)     + w * 4 * (K_DIM / 4);
    const float bt = bterm[0];

    f32x4 xa[16], xb[16];
    LOADB(xa, 0);

    LOADB(xb, 1); PROCESS(xa, 0);
    LOADB(xa, 2); PROCESS(xb, 1);
    LOADB(xb, 3); PROCESS(xa, 2);
    PROCESS(xb, 3);
}

extern "C" void kernel_launch(void* const* d_in, const int* in_sizes, int n_in,
                              void* d_out, int out_size, void* d_ws, size_t ws_size,
                              hipStream_t stream) {
    const float* x        = (const float*)d_in[0];   // (M, K)
    const float* W        = (const float*)d_in[1];   // (K, N)
    const float* bias     = (const float*)d_in[2];   // (N,)
    const float* subtract = (const float*)d_in[3];   // (N,)
    float* out = (float*)d_out;

    float* c     = (float*)d_ws;          // K_DIM floats
    float* bterm = c + K_DIM;             // 1 float

    const int M = in_sizes[0] / K_DIM;    // 16384

    colsum_kernel<<<K_DIM + 1, 256, 0, stream>>>(W, bias, subtract, c, bterm);
    rowfuse_kernel<<<M / 16, 256, 0, stream>>>(x, c, bterm, out);  // 1024 blocks
}